// Round 3
// baseline (294.626 us; speedup 1.0000x reference)
//
#include <hip/hip_runtime.h>
#include <stdint.h>

#define N_ROWS 8192
#define DIM    128
#define NCODES 16384
#define TAU    0.01f
#define MARGIN 0.20f
#define CAP    256

typedef __attribute__((ext_vector_type(4))) float f32x4;
typedef __attribute__((ext_vector_type(8))) short s16x8;

// ---------------- workspace layout (bytes) ----------------
// [0, 2 MiB)        : x_bf16  swizzled (tile-fragment order)
// [2 MiB, 6 MiB)    : cb_bf16 swizzled (tile-fragment order)
// [6 MiB, +32 KiB)  : cnt  int[8192]
// [8 MiB, 16 MiB)   : cand int[8192*256]

__device__ inline unsigned short f2bf(float f) {
    union { float f; unsigned int u; } v; v.f = f;
    unsigned int r = v.u + 0x7FFFu + ((v.u >> 16) & 1u);  // RNE
    return (unsigned short)(r >> 16);
}

__device__ inline void async16(const void* g, void* l) {
    __builtin_amdgcn_global_load_lds(
        (const __attribute__((address_space(1))) void*)g,
        (__attribute__((address_space(3))) void*)l, 16, 0, 0);
}

// ---------------- kernel A: convert + swizzle to fragment order + zero cnt ----------------
// Fragment order: flat = ((tile*4 + kk)*64 + lane)*8 + e
//   tile = row/16, r = lane&15, q = lane>>4, src = M[tile*16+r][kk*32+q*8+e]
#define XGROUPS  131072   // 8192*128/8
#define CBGROUPS 262144   // 16384*128/8
__global__ void convert_kernel(const float* __restrict__ x, const float* __restrict__ cb,
                               unsigned short* __restrict__ xbf, unsigned short* __restrict__ cbbf,
                               int* __restrict__ cnt) {
    int gid = blockIdx.x * blockDim.x + threadIdx.x;
    if (gid < XGROUPS + CBGROUPS) {
        const float* src; unsigned short* dst; int g;
        if (gid < XGROUPS) { g = gid; src = x; dst = xbf; }
        else               { g = gid - XGROUPS; src = cb; dst = cbbf; }
        const int t = g >> 8, within = g & 255;
        const int kk = within >> 6, ln = within & 63;
        const int r = ln & 15, q = ln >> 4;
        const float* p = src + ((size_t)(t * 16 + r) * DIM + kk * 32 + q * 8);
        s16x8 v;
#pragma unroll
        for (int e = 0; e < 8; ++e) v[e] = (short)f2bf(p[e]);
        *reinterpret_cast<s16x8*>(dst + (size_t)g * 8) = v;
    } else {
        int c = gid - (XGROUPS + CBGROUPS);
        if (c < N_ROWS) cnt[c] = 0;
    }
}

// ---------------- kernel B: m97-style 2-buffer MFMA scores + candidate emission ----------------
// Block: 4 waves, 128 x-rows (register-resident B frags) x 2048 cb rows.
// Grid = 64 rowgroups x 8 csplits = 512 blocks = 2/CU. csplit = blockIdx&7 -> XCD-local cb strip.
// Per iteration: stage 64 cb rows (16 KB) into LDS buf^1 via global_load_lds while computing buf.
__global__ __launch_bounds__(256, 2) void gemm_topk_kernel(
        const unsigned short* __restrict__ xbf, const unsigned short* __restrict__ cbbf,
        int* __restrict__ cnt, int* __restrict__ cand) {
    __shared__ short buf[2][8192];   // 2 x 16 KB cb tiles (4 sub-tiles of 16 rows each)
    __shared__ int rm[128];          // int-punned running x-row max

    const int wave = threadIdx.x >> 6, lane = threadIdx.x & 63;
    const int r = lane & 15, q = lane >> 4;
    const int csplit = blockIdx.x & 7, rowgrp = blockIdx.x >> 3;
    const int row0 = rowgrp * 128;

    if (threadIdx.x < 128) rm[threadIdx.x] = (int)0x80000000u;  // -0.0f

    // B fragments (x rows), register-resident for the whole block: 8 x-tiles x 4 kk
    s16x8 bf[8][4];
#pragma unroll
    for (int xt = 0; xt < 8; ++xt)
#pragma unroll
        for (int kk = 0; kk < 4; ++kk)
            bf[xt][kk] = *reinterpret_cast<const s16x8*>(
                xbf + (((size_t)(rowgrp * 8 + xt) * 4 + kk) * 64 + lane) * 8);

    // stage(it, b): wave w stages cb sub-tile w of iteration it into buf[b]
    // cb tile t (16 rows) = 4 KB contiguous at cbbf + t*2048 shorts.
#define STAGE(IT, B)                                                              \
    {                                                                             \
        const unsigned short* g =                                                 \
            cbbf + (size_t)(csplit * 128 + (IT) * 4 + wave) * 2048 + lane * 8;    \
        short* l = &buf[B][wave * 2048];                                          \
        _Pragma("unroll")                                                         \
        for (int i = 0; i < 4; ++i) async16(g + i * 512, l + i * 512);            \
    }

    STAGE(0, 0)

    float rmv[8];
#pragma unroll
    for (int xt = 0; xt < 8; ++xt) rmv[xt] = -0.f;

#pragma unroll 2
    for (int it = 0; it < 32; ++it) {
        __syncthreads();                       // tile `it` landed; buf^1 readers of it-1 done
        if (it < 31) STAGE(it + 1, (it + 1) & 1)

        // LDS -> A fragments (this wave's 16 cb rows)
        const s16x8* lp = reinterpret_cast<const s16x8*>(&buf[it & 1][wave * 2048]);
        s16x8 af[4];
#pragma unroll
        for (int kk = 0; kk < 4; ++kk) af[kk] = lp[kk * 64 + lane];

        f32x4 acc[8];
#pragma unroll
        for (int xt = 0; xt < 8; ++xt) acc[xt] = (f32x4){0.f, 0.f, 0.f, 0.f};
#pragma unroll
        for (int kk = 0; kk < 4; ++kk)
#pragma unroll
            for (int xt = 0; xt < 8; ++xt)
                acc[xt] = __builtin_amdgcn_mfma_f32_16x16x32_bf16(
                    af[kk], bf[xt][kk], acc[xt], 0, 0, 0);

        // per-xt lane max; update running max
        float mx[8];
#pragma unroll
        for (int xt = 0; xt < 8; ++xt) {
            mx[xt] = fmaxf(fmaxf(acc[xt][0], acc[xt][1]), fmaxf(acc[xt][2], acc[xt][3]));
            if (mx[xt] > rmv[xt]) {
                rmv[xt] = mx[xt];
                atomicMax(&rm[xt * 16 + r], __float_as_int(mx[xt]));
            }
        }
        if (it == 0) {                          // warm thresholds block-wide before first emission
            __syncthreads();
#pragma unroll
            for (int xt = 0; xt < 8; ++xt) rmv[xt] = __int_as_float(rm[xt * 16 + r]);
        }

        // emission (rare)
        const int crow0 = csplit * 2048 + it * 64 + wave * 16 + q * 4;
#pragma unroll
        for (int xt = 0; xt < 8; ++xt) {
            if (mx[xt] > rmv[xt] - MARGIN) {
                rmv[xt] = fmaxf(rmv[xt], __int_as_float(rm[xt * 16 + r]));
                const float thr = rmv[xt] - MARGIN;
                if (mx[xt] > thr) {
                    const int grow = row0 + xt * 16 + r;
#pragma unroll
                    for (int j = 0; j < 4; ++j)
                        if (acc[xt][j] > thr) {
                            int pos = atomicAdd(&cnt[grow], 1);
                            if (pos < CAP) cand[(size_t)grow * CAP + pos] = crow0 + j;
                        }
                }
            }
        }
    }
#undef STAGE
}

// ---------------- kernel C: exact fp32 rescore + top-3 + softmax + combine ----------------
__device__ inline void topk3_insert(float s, int i, float& s1, int& i1,
                                    float& s2, int& i2, float& s3, int& i3) {
    if (s > s1 || (s == s1 && i < i1)) {
        s3 = s2; i3 = i2; s2 = s1; i2 = i1; s1 = s; i1 = i;
    } else if (s > s2 || (s == s2 && i < i2)) {
        s3 = s2; i3 = i2; s2 = s; i2 = i;
    } else if (s > s3 || (s == s3 && i < i3)) {
        s3 = s; i3 = i;
    }
}

__global__ __launch_bounds__(256) void finalize_kernel(
        const float* __restrict__ x, const float* __restrict__ cb,
        const int* __restrict__ cnt, const int* __restrict__ cand,
        float* __restrict__ out) {
    const int lane = threadIdx.x & 63;
    const int row  = blockIdx.x * 4 + (threadIdx.x >> 6);
    const int sub  = lane & 7;   // 8 lanes per candidate, 16 dims each
    const int grp  = lane >> 3;  // 8 candidates in flight

    int c = cnt[row];
    if (c > CAP) c = CAP;
    if (c < 0) c = 0;

    float4 xq[4];
#pragma unroll
    for (int k = 0; k < 4; ++k)
        xq[k] = ((const float4*)x)[(size_t)row * 32 + sub * 4 + k];

    const int BIGI = 0x3FFFFFFF;
    float s1 = -1e30f, s2 = -1e30f, s3 = -1e30f;
    int   i1 = BIGI,   i2 = BIGI,   i3 = BIGI;

    const int rounds = (c + 7) >> 3;
    for (int t = 0; t < rounds; ++t) {
        const int ci  = t * 8 + grp;
        const int idx = (ci < c) ? cand[(size_t)row * CAP + ci] : -1;
        float p = 0.f;
        if (idx >= 0) {
            const float4* cbp = (const float4*)cb + (size_t)idx * 32 + sub * 4;
#pragma unroll
            for (int k = 0; k < 4; ++k) {
                float4 cv = cbp[k];
                p += xq[k].x * cv.x + xq[k].y * cv.y + xq[k].z * cv.z + xq[k].w * cv.w;
            }
        }
        p += __shfl_xor(p, 1);
        p += __shfl_xor(p, 2);
        p += __shfl_xor(p, 4);
        if (idx >= 0) topk3_insert(p, idx, s1, i1, s2, i2, s3, i3);
    }

    float fs1 = -1e30f, fs2 = -1e30f, fs3 = -1e30f;
    int   fi1 = BIGI,   fi2 = BIGI,   fi3 = BIGI;
#pragma unroll
    for (int g = 0; g < 8; ++g) {
        float a1 = __shfl(s1, g * 8); int b1 = __shfl(i1, g * 8);
        float a2 = __shfl(s2, g * 8); int b2 = __shfl(i2, g * 8);
        float a3 = __shfl(s3, g * 8); int b3 = __shfl(i3, g * 8);
        topk3_insert(a1, b1, fs1, fi1, fs2, fi2, fs3, fi3);
        topk3_insert(a2, b2, fs1, fi1, fs2, fi2, fs3, fi3);
        topk3_insert(a3, b3, fs1, fi1, fs2, fi2, fs3, fi3);
    }

    const float m  = fmaxf(fs1, 0.f);
    const float e1 = (fi1 != BIGI) ? __expf((fs1 - m) / TAU) : 0.f;
    const float e2 = (fi2 != BIGI) ? __expf((fs2 - m) / TAU) : 0.f;
    const float e3 = (fi3 != BIGI) ? __expf((fs3 - m) / TAU) : 0.f;
    const float denom = e1 + e2 + e3 + (float)(NCODES - 3) * __expf(-m / TAU);
    const float w1 = e1 / denom, w2 = e2 / denom, w3 = e3 / denom;

    const float2* cb2 = (const float2*)cb;
    float ox = 0.f, oy = 0.f;
    if (fi1 != BIGI) { float2 v = cb2[(size_t)fi1 * 64 + lane]; ox += w1 * v.x; oy += w1 * v.y; }
    if (fi2 != BIGI) { float2 v = cb2[(size_t)fi2 * 64 + lane]; ox += w2 * v.x; oy += w2 * v.y; }
    if (fi3 != BIGI) { float2 v = cb2[(size_t)fi3 * 64 + lane]; ox += w3 * v.x; oy += w3 * v.y; }
    ((float2*)out)[(size_t)row * 64 + lane] = make_float2(ox, oy);
}

// ---------------- launch ----------------
extern "C" void kernel_launch(void* const* d_in, const int* in_sizes, int n_in,
                              void* d_out, int out_size, void* d_ws, size_t ws_size,
                              hipStream_t stream) {
    const float* x  = (const float*)d_in[0];
    const float* cb = (const float*)d_in[1];
    char* ws = (char*)d_ws;

    unsigned short* xbf  = (unsigned short*)ws;                  // 2 MiB
    unsigned short* cbbf = (unsigned short*)(ws + (2u << 20));   // 4 MiB
    int* cnt  = (int*)(ws + (6u << 20));                         // 32 KiB
    int* cand = (int*)(ws + (8u << 20));                         // 8 MiB
    float* out = (float*)d_out;

    hipLaunchKernelGGL(convert_kernel,   dim3(1568), dim3(256), 0, stream, x, cb, xbf, cbbf, cnt);
    hipLaunchKernelGGL(gemm_topk_kernel, dim3(512),  dim3(256), 0, stream, xbf, cbbf, cnt, cand);
    hipLaunchKernelGGL(finalize_kernel,  dim3(2048), dim3(256), 0, stream, x, cb, cnt, cand, out);
}

// Round 4
// 149.217 us; speedup vs baseline: 1.9745x; 1.9745x over previous
//
#include <hip/hip_runtime.h>
#include <stdint.h>

#define N_ROWS 8192
#define DIM    128
#define NCODES 16384
#define TAU    0.01f
#define MARGIN_EMIT 0.16f   // emit if bf16 score > approx_rowmax - this
#define RESCORE_WIN 0.15f   // finalize: exact-rescore keys within this of key-max
#define CAP    256

typedef __attribute__((ext_vector_type(4))) float f32x4;
typedef __attribute__((ext_vector_type(8))) short s16x8;

// ---------------- workspace layout (bytes) ----------------
// [0, 2 MiB)            : xbf  swizzled bf16 (fragment order)
// [2 MiB, 6 MiB)        : cbbf swizzled bf16 (fragment order)
// [6 MiB, +32 KiB)      : cnt  int[8192]
// [6 MiB+128K, +32 KiB) : thr  int[8192] (int-punned float, seeded approx row max)
// [8 MiB, 16 MiB)       : cand uint[8192*256] packed (score18<<14 | idx)

__device__ inline unsigned short f2bf(float f) {
    union { float f; unsigned int u; } v; v.f = f;
    unsigned int r = v.u + 0x7FFFu + ((v.u >> 16) & 1u);  // RNE
    return (unsigned short)(r >> 16);
}

// ---------------- kernel A: convert + swizzle + zero cnt/thr ----------------
// Fragment order: flat = ((tile*4 + kk)*64 + lane)*8 + e
//   tile = row/16, r = lane&15, q = lane>>4, src = M[tile*16+r][kk*32+q*8+e]
#define XGROUPS  131072   // 8192*128/8
#define CBGROUPS 262144   // 16384*128/8
__global__ void convert_kernel(const float* __restrict__ x, const float* __restrict__ cb,
                               unsigned short* __restrict__ xbf, unsigned short* __restrict__ cbbf,
                               int* __restrict__ cnt, int* __restrict__ thr) {
    int gid = blockIdx.x * blockDim.x + threadIdx.x;
    if (gid < XGROUPS + CBGROUPS) {
        const float* src; unsigned short* dst; int g;
        if (gid < XGROUPS) { g = gid; src = x; dst = xbf; }
        else               { g = gid - XGROUPS; src = cb; dst = cbbf; }
        const int t = g >> 8, within = g & 255;
        const int kk = within >> 6, ln = within & 63;
        const int r = ln & 15, q = ln >> 4;
        const float* p = src + ((size_t)(t * 16 + r) * DIM + kk * 32 + q * 8);
        s16x8 v;
#pragma unroll
        for (int e = 0; e < 8; ++e) v[e] = (short)f2bf(p[e]);
        *reinterpret_cast<s16x8*>(dst + (size_t)g * 8) = v;
    } else {
        int i = gid - (XGROUPS + CBGROUPS);
        if (i < N_ROWS) cnt[i] = 0;
        else if (i < 2 * N_ROWS) thr[i - N_ROWS] = 0;   // 0.0f bits; scores' max > 0 always
    }
}

// ---------------- kernel S: seed approx per-row max over cb rows [0, 2048) ----------------
// Grid 512 = 128 rowgroups(64 rows) x 4 csplits; wave scans 8 tiles (128 cb rows).
__global__ __launch_bounds__(256, 2) void seed_kernel(
        const unsigned short* __restrict__ xbf, const unsigned short* __restrict__ cbbf,
        int* __restrict__ thr) {
    __shared__ int rm[64];
    const int wave = threadIdx.x >> 6, lane = threadIdx.x & 63;
    const int r = lane & 15;
    const int rowgrp = blockIdx.x >> 2, csplit = blockIdx.x & 3;
    if (threadIdx.x < 64) rm[threadIdx.x] = 0;
    __syncthreads();

    s16x8 bf[4][4];
#pragma unroll
    for (int xt = 0; xt < 4; ++xt)
#pragma unroll
        for (int kk = 0; kk < 4; ++kk)
            bf[xt][kk] = *reinterpret_cast<const s16x8*>(
                xbf + (((size_t)(rowgrp * 4 + xt) * 4 + kk) * 64 + lane) * 8);

    float mxv[4] = {0.f, 0.f, 0.f, 0.f};
    const int t0 = (csplit * 4 + wave) * 8;   // tiles 0..127 -> cb rows 0..2047
#pragma unroll 2
    for (int t = 0; t < 8; ++t) {
        const s16x8* ap = reinterpret_cast<const s16x8*>(cbbf + (size_t)(t0 + t) * 2048);
        s16x8 af[4];
#pragma unroll
        for (int kk = 0; kk < 4; ++kk) af[kk] = ap[kk * 64 + lane];
        f32x4 acc[4];
#pragma unroll
        for (int xt = 0; xt < 4; ++xt) acc[xt] = (f32x4){0.f, 0.f, 0.f, 0.f};
#pragma unroll
        for (int kk = 0; kk < 4; ++kk)
#pragma unroll
            for (int xt = 0; xt < 4; ++xt)
                acc[xt] = __builtin_amdgcn_mfma_f32_16x16x32_bf16(
                    af[kk], bf[xt][kk], acc[xt], 0, 0, 0);
#pragma unroll
        for (int xt = 0; xt < 4; ++xt)
            mxv[xt] = fmaxf(mxv[xt],
                fmaxf(fmaxf(acc[xt][0], acc[xt][1]), fmaxf(acc[xt][2], acc[xt][3])));
    }
#pragma unroll
    for (int xt = 0; xt < 4; ++xt)
        atomicMax(&rm[xt * 16 + r], __float_as_int(mxv[xt]));
    __syncthreads();
    if (threadIdx.x < 64)
        atomicMax(&thr[rowgrp * 64 + threadIdx.x], rm[threadIdx.x]);
}

// ---------------- kernel B: wave-independent, barrier-free MFMA scan ----------------
// Grid 512 = 64 rowgroups(128 x-rows) x 8 csplits. Block = 4 waves; wave scans 32 cb tiles
// (csplit strip of 2048 cb rows / 4 waves), direct global->VGPR loads double-buffered 1 tile ahead.
__global__ __launch_bounds__(256, 2) void gemm_topk_kernel(
        const unsigned short* __restrict__ xbf, const unsigned short* __restrict__ cbbf,
        const int* __restrict__ thr, int* __restrict__ cnt, unsigned int* __restrict__ cand) {
    const int wave = threadIdx.x >> 6, lane = threadIdx.x & 63;
    const int r = lane & 15, q = lane >> 4;
    const int rowgrp = blockIdx.x >> 3, csplit = blockIdx.x & 7;
    const int row0 = rowgrp * 128;

    // x fragments register-resident: 8 x-tiles x 4 k-steps = 128 VGPRs
    s16x8 bf[8][4];
#pragma unroll
    for (int xt = 0; xt < 8; ++xt)
#pragma unroll
        for (int kk = 0; kk < 4; ++kk)
            bf[xt][kk] = *reinterpret_cast<const s16x8*>(
                xbf + (((size_t)(rowgrp * 8 + xt) * 4 + kk) * 64 + lane) * 8);

    // fixed emission thresholds (seeded approx max - margin)
    float thrv[8];
#pragma unroll
    for (int xt = 0; xt < 8; ++xt)
        thrv[xt] = __int_as_float(thr[row0 + xt * 16 + r]) - MARGIN_EMIT;

    const int t0 = csplit * 128 + wave * 32;   // wave's 32 cb tiles (512 cb rows)
    const s16x8* base = reinterpret_cast<const s16x8*>(cbbf);

    s16x8 af[2][4];
#pragma unroll
    for (int kk = 0; kk < 4; ++kk) af[0][kk] = base[(size_t)t0 * 256 + kk * 64 + lane];

#pragma unroll 2
    for (int t = 0; t < 32; ++t) {
        if (t < 31) {
            const s16x8* ap = base + (size_t)(t0 + t + 1) * 256 + lane;
#pragma unroll
            for (int kk = 0; kk < 4; ++kk) af[(t + 1) & 1][kk] = ap[kk * 64];
        }
        const s16x8* cur = af[t & 1];

        f32x4 acc[8];
#pragma unroll
        for (int xt = 0; xt < 8; ++xt) acc[xt] = (f32x4){0.f, 0.f, 0.f, 0.f};
#pragma unroll
        for (int kk = 0; kk < 4; ++kk)
#pragma unroll
            for (int xt = 0; xt < 8; ++xt)
                acc[xt] = __builtin_amdgcn_mfma_f32_16x16x32_bf16(
                    cur[kk], bf[xt][kk], acc[xt], 0, 0, 0);

        // fixed-threshold emission (rare: ~6 per row over the whole scan)
        const int cbase = (t0 + t) * 16 + q * 4;
#pragma unroll
        for (int xt = 0; xt < 8; ++xt) {
            const float mx = fmaxf(fmaxf(acc[xt][0], acc[xt][1]),
                                   fmaxf(acc[xt][2], acc[xt][3]));
            if (mx > thrv[xt]) {
                const int grow = row0 + xt * 16 + r;
#pragma unroll
                for (int j = 0; j < 4; ++j)
                    if (acc[xt][j] > thrv[xt]) {
                        int pos = atomicAdd(&cnt[grow], 1);
                        if (pos < CAP) {
                            // score > 0 here, so float bits are monotone
                            unsigned int key = ((__float_as_uint(acc[xt][j]) >> 13) << 14)
                                             | (unsigned int)(cbase + j);
                            cand[(size_t)grow * CAP + pos] = key;
                        }
                    }
            }
        }
    }
}

// ---------------- kernel C: key scan + exact fp32 rescore of near-max + softmax ----------------
__device__ inline void topk3_insert(float s, int i, float& s1, int& i1,
                                    float& s2, int& i2, float& s3, int& i3) {
    if (s > s1 || (s == s1 && i < i1)) {
        s3 = s2; i3 = i2; s2 = s1; i2 = i1; s1 = s; i1 = i;
    } else if (s > s2 || (s == s2 && i < i2)) {
        s3 = s2; i3 = i2; s2 = s; i2 = i;
    } else if (s > s3 || (s == s3 && i < i3)) {
        s3 = s; i3 = i;
    }
}

__device__ inline float dec_key(unsigned int k) {
    return __uint_as_float((k >> 14) << 13);
}

__global__ __launch_bounds__(256) void finalize_kernel(
        const float* __restrict__ x, const float* __restrict__ cb,
        const int* __restrict__ cnt, const unsigned int* __restrict__ cand,
        float* __restrict__ out) {
    const int lane = threadIdx.x & 63;
    const int row  = blockIdx.x * 4 + (threadIdx.x >> 6);

    int c = cnt[row];
    if (c > CAP) c = CAP;
    if (c < 0) c = 0;

    const float2 xv = ((const float2*)x)[(size_t)row * 64 + lane];

    // pass 1: max key (coalesced)
    unsigned int kmax = 0;
    for (int i = lane; i < c; i += 64)
        kmax = max(kmax, cand[(size_t)row * CAP + i]);
#pragma unroll
    for (int d = 1; d < 64; d <<= 1)
        kmax = max(kmax, (unsigned int)__shfl_xor((int)kmax, d));
    const float rthr = dec_key(kmax) - RESCORE_WIN;

    // pass 2: exact-rescore candidates near the max (expected ~2)
    const int BIGI = 0x3FFFFFFF;
    float fs1 = -1e30f, fs2 = -1e30f, fs3 = -1e30f;
    int   fi1 = BIGI,   fi2 = BIGI,   fi3 = BIGI;
    for (int basei = 0; basei < c; basei += 64) {
        const int i = basei + lane;
        unsigned int key = (i < c) ? cand[(size_t)row * CAP + i] : 0u;
        const bool flag = (i < c) && (dec_key(key) > rthr);
        unsigned long long mask = __ballot(flag);
        while (mask) {
            const int b = __ffsll((long long)mask) - 1;
            mask &= mask - 1;
            const int idx = __shfl((int)(key & 16383u), b);
            const float2 cv = ((const float2*)cb)[(size_t)idx * 64 + lane];
            float p = xv.x * cv.x + xv.y * cv.y;
#pragma unroll
            for (int d = 1; d < 64; d <<= 1) p += __shfl_xor(p, d);
            topk3_insert(p, idx, fs1, fi1, fs2, fi2, fs3, fi3);
        }
    }

    // exact softmax over {top-3} U {C-3 zeros}
    const float m  = fmaxf(fs1, 0.f);
    const float e1 = (fi1 != BIGI) ? __expf((fs1 - m) / TAU) : 0.f;
    const float e2 = (fi2 != BIGI) ? __expf((fs2 - m) / TAU) : 0.f;
    const float e3 = (fi3 != BIGI) ? __expf((fs3 - m) / TAU) : 0.f;
    const float denom = e1 + e2 + e3 + (float)(NCODES - 3) * __expf(-m / TAU);
    const float w1 = e1 / denom, w2 = e2 / denom, w3 = e3 / denom;

    const float2* cb2 = (const float2*)cb;
    float ox = 0.f, oy = 0.f;
    if (fi1 != BIGI) { float2 v = cb2[(size_t)fi1 * 64 + lane]; ox += w1 * v.x; oy += w1 * v.y; }
    if (fi2 != BIGI) { float2 v = cb2[(size_t)fi2 * 64 + lane]; ox += w2 * v.x; oy += w2 * v.y; }
    if (fi3 != BIGI) { float2 v = cb2[(size_t)fi3 * 64 + lane]; ox += w3 * v.x; oy += w3 * v.y; }
    ((float2*)out)[(size_t)row * 64 + lane] = make_float2(ox, oy);
}

// ---------------- launch ----------------
extern "C" void kernel_launch(void* const* d_in, const int* in_sizes, int n_in,
                              void* d_out, int out_size, void* d_ws, size_t ws_size,
                              hipStream_t stream) {
    const float* x  = (const float*)d_in[0];
    const float* cb = (const float*)d_in[1];
    char* ws = (char*)d_ws;

    unsigned short* xbf  = (unsigned short*)ws;                         // 2 MiB
    unsigned short* cbbf = (unsigned short*)(ws + (2u << 20));          // 4 MiB
    int* cnt  = (int*)(ws + (6u << 20));                                // 32 KiB
    int* thr  = (int*)(ws + (6u << 20) + (128u << 10));                 // 32 KiB
    unsigned int* cand = (unsigned int*)(ws + (8u << 20));              // 8 MiB
    float* out = (float*)d_out;

    hipLaunchKernelGGL(convert_kernel,   dim3(1600), dim3(256), 0, stream, x, cb, xbf, cbbf, cnt, thr);
    hipLaunchKernelGGL(seed_kernel,      dim3(512),  dim3(256), 0, stream, xbf, cbbf, thr);
    hipLaunchKernelGGL(gemm_topk_kernel, dim3(512),  dim3(256), 0, stream, xbf, cbbf, thr, cnt, cand);
    hipLaunchKernelGGL(finalize_kernel,  dim3(2048), dim3(256), 0, stream, x, cb, cnt, cand, out);
}